// Round 2
// baseline (115.601 us; speedup 1.0000x reference)
//
#include <hip/hip_runtime.h>
#include <math.h>

// out[b] = -1000 * sum_{t,x,y} (inp-x)^2 over finite entries of inp.
// x, inp: fp32 [8, 15, 512, 512]. Pure HBM-bound reduction (251.7 MB read).
// Single fused kernel: grid-stride partials + per-batch last-block final reduce.

constexpr int N_B = 8;
constexpr long long N_PER_BATCH = 15LL * 512 * 512;        // 3,932,160
constexpr int BLOCKS_PER_BATCH = 256;
constexpr int THREADS = 256;
constexpr int STRIDE = BLOCKS_PER_BATCH * THREADS;         // 65,536
constexpr int TRIPS = (int)(N_PER_BATCH / 4 / STRIDE);     // 983,040 / 65,536 = 15
constexpr float NEG_INV_NOISE = -1000.0f;

__device__ __forceinline__ float wave_reduce_add(float v) {
    #pragma unroll
    for (int off = 32; off > 0; off >>= 1)
        v += __shfl_down(v, off, 64);
    return v;
}

__device__ __forceinline__ float block_reduce_add(float v, float* lds) {
    v = wave_reduce_add(v);
    const int lane = threadIdx.x & 63;
    const int wave = threadIdx.x >> 6;
    if (lane == 0) lds[wave] = v;
    __syncthreads();
    float s = 0.0f;
    if (threadIdx.x == 0) {
        #pragma unroll
        for (int w = 0; w < THREADS / 64; ++w) s += lds[w];
    }
    return s;  // valid in thread 0 only
}

__global__ __launch_bounds__(THREADS)
void nlpobs_fused(const float* __restrict__ x,
                  const float* __restrict__ inp,
                  float* __restrict__ partial,
                  unsigned int* __restrict__ counters,
                  float* __restrict__ out) {
    const int b   = blockIdx.x / BLOCKS_PER_BATCH;
    const int blk = blockIdx.x % BLOCKS_PER_BATCH;

    const float4* __restrict__ x4 = reinterpret_cast<const float4*>(x   + (size_t)b * N_PER_BATCH);
    const float4* __restrict__ i4 = reinterpret_cast<const float4*>(inp + (size_t)b * N_PER_BATCH);

    float acc = 0.0f;
    const int base = blk * THREADS + threadIdx.x;
    #pragma unroll 3
    for (int k = 0; k < TRIPS; ++k) {
        const int i = base + k * STRIDE;
        float4 xv = x4[i];
        float4 iv = i4[i];
        float d0 = iv.x - xv.x;
        float d1 = iv.y - xv.y;
        float d2 = iv.z - xv.z;
        float d3 = iv.w - xv.w;
        acc += isfinite(iv.x) ? d0 * d0 : 0.0f;
        acc += isfinite(iv.y) ? d1 * d1 : 0.0f;
        acc += isfinite(iv.z) ? d2 * d2 : 0.0f;
        acc += isfinite(iv.w) ? d3 * d3 : 0.0f;
    }

    __shared__ float lds[THREADS / 64];
    __shared__ bool is_last;
    float s = block_reduce_add(acc, lds);

    if (threadIdx.x == 0) {
        partial[blockIdx.x] = s;            // b * BLOCKS_PER_BATCH + blk
        __threadfence();                    // make partial visible device-wide
        unsigned int prev = atomicAdd(&counters[b], 1u);
        is_last = (prev == BLOCKS_PER_BATCH - 1);
    }
    __syncthreads();
    if (!is_last) return;

    // Last block of this batch: all other partials are visible (each writer
    // fenced before its atomicAdd). Fixed-order tree reduce -> deterministic.
    __threadfence();
    float v = partial[b * BLOCKS_PER_BATCH + threadIdx.x];
    __syncthreads();                        // lds reuse hazard
    float total = block_reduce_add(v, lds);
    if (threadIdx.x == 0) out[b] = NEG_INV_NOISE * total;
}

extern "C" void kernel_launch(void* const* d_in, const int* in_sizes, int n_in,
                              void* d_out, int out_size, void* d_ws, size_t ws_size,
                              hipStream_t stream) {
    const float* x   = (const float*)d_in[0];
    const float* inp = (const float*)d_in[1];
    float* out       = (float*)d_out;

    float* partial         = (float*)d_ws;                                  // 2048 floats
    unsigned int* counters = (unsigned int*)((char*)d_ws + 2048 * sizeof(float));  // 8 uints

    hipMemsetAsync(counters, 0, N_B * sizeof(unsigned int), stream);
    nlpobs_fused<<<N_B * BLOCKS_PER_BATCH, THREADS, 0, stream>>>(x, inp, partial, counters, out);
}

// Round 3
// 42.353 us; speedup vs baseline: 2.7295x; 2.7295x over previous
//
#include <hip/hip_runtime.h>
#include <math.h>

// out[b] = -1000 * sum_{t,x,y} (inp-x)^2 over finite entries of inp.
// x, inp: fp32 [8, 15, 512, 512]. HBM/L3-bound reduction (251.7 MB logical read,
// ~126 MB from HBM, rest L3-resident). Two-kernel deterministic tree reduce.
// Round-2 lesson: NO __threadfence / device fences — they invalidate L2 across
// XCDs and halved streaming BW.

constexpr int N_B = 8;
constexpr long long N_PER_BATCH = 15LL * 512 * 512;        // 3,932,160
constexpr int BLOCKS_PER_BATCH = 256;
constexpr int THREADS = 256;
constexpr int STRIDE = BLOCKS_PER_BATCH * THREADS;         // 65,536 float4s
constexpr int TRIPS = (int)(N_PER_BATCH / 4 / STRIDE);     // 15
constexpr float NEG_INV_NOISE = -1000.0f;

__device__ __forceinline__ float wave_reduce_add(float v) {
    #pragma unroll
    for (int off = 32; off > 0; off >>= 1)
        v += __shfl_down(v, off, 64);
    return v;
}

__device__ __forceinline__ float sq_masked(float iv, float xv) {
    float d = iv - xv;
    return isfinite(iv) ? d * d : 0.0f;
}

__device__ __forceinline__ float sq4(float4 iv, float4 xv) {
    return sq_masked(iv.x, xv.x) + sq_masked(iv.y, xv.y)
         + sq_masked(iv.z, xv.z) + sq_masked(iv.w, xv.w);
}

__global__ __launch_bounds__(THREADS)
void nlpobs_partial(const float* __restrict__ x,
                    const float* __restrict__ inp,
                    float* __restrict__ partial) {
    const int b   = blockIdx.x / BLOCKS_PER_BATCH;
    const int blk = blockIdx.x % BLOCKS_PER_BATCH;

    const float4* __restrict__ x4 = reinterpret_cast<const float4*>(x   + (size_t)b * N_PER_BATCH);
    const float4* __restrict__ i4 = reinterpret_cast<const float4*>(inp + (size_t)b * N_PER_BATCH);
    const int base = blk * THREADS + threadIdx.x;

    // 15 trips = 3 groups of 5. Explicit 5-wide unroll: 10 dwordx4 loads in
    // flight per group, 5 rotating accumulators -> deep MLP, VGPR ~50 (< 64,
    // keeps 8 waves/SIMD).
    float a0 = 0.0f, a1 = 0.0f, a2 = 0.0f, a3 = 0.0f, a4 = 0.0f;
    #pragma unroll
    for (int g = 0; g < 3; ++g) {
        const int i0 = base + (5 * g + 0) * STRIDE;
        const int i1 = base + (5 * g + 1) * STRIDE;
        const int i2 = base + (5 * g + 2) * STRIDE;
        const int i3 = base + (5 * g + 3) * STRIDE;
        const int i4i = base + (5 * g + 4) * STRIDE;
        float4 xv0 = x4[i0], iv0 = i4[i0];
        float4 xv1 = x4[i1], iv1 = i4[i1];
        float4 xv2 = x4[i2], iv2 = i4[i2];
        float4 xv3 = x4[i3], iv3 = i4[i3];
        float4 xv4 = x4[i4i], iv4 = i4[i4i];
        a0 += sq4(iv0, xv0);
        a1 += sq4(iv1, xv1);
        a2 += sq4(iv2, xv2);
        a3 += sq4(iv3, xv3);
        a4 += sq4(iv4, xv4);
    }
    float acc = ((a0 + a1) + (a2 + a3)) + a4;

    acc = wave_reduce_add(acc);
    __shared__ float lds[THREADS / 64];
    const int lane = threadIdx.x & 63;
    const int wave = threadIdx.x >> 6;
    if (lane == 0) lds[wave] = acc;
    __syncthreads();
    if (threadIdx.x == 0) {
        float s = 0.0f;
        #pragma unroll
        for (int w = 0; w < THREADS / 64; ++w) s += lds[w];
        partial[blockIdx.x] = s;
    }
}

__global__ __launch_bounds__(THREADS)
void nlpobs_final(const float* __restrict__ partial,
                  float* __restrict__ out) {
    const int b = blockIdx.x;
    float acc = partial[b * BLOCKS_PER_BATCH + threadIdx.x];
    acc = wave_reduce_add(acc);
    __shared__ float lds[THREADS / 64];
    const int lane = threadIdx.x & 63;
    const int wave = threadIdx.x >> 6;
    if (lane == 0) lds[wave] = acc;
    __syncthreads();
    if (threadIdx.x == 0) {
        float s = 0.0f;
        #pragma unroll
        for (int w = 0; w < THREADS / 64; ++w) s += lds[w];
        out[b] = NEG_INV_NOISE * s;
    }
}

extern "C" void kernel_launch(void* const* d_in, const int* in_sizes, int n_in,
                              void* d_out, int out_size, void* d_ws, size_t ws_size,
                              hipStream_t stream) {
    const float* x   = (const float*)d_in[0];
    const float* inp = (const float*)d_in[1];
    float* out       = (float*)d_out;
    float* partial   = (float*)d_ws;                        // 8 KB

    nlpobs_partial<<<N_B * BLOCKS_PER_BATCH, THREADS, 0, stream>>>(x, inp, partial);
    nlpobs_final<<<N_B, THREADS, 0, stream>>>(partial, out);
}